// Round 2
// baseline (1834.767 us; speedup 1.0000x reference)
//
#include <hip/hip_runtime.h>

// Correlation layer: out[b,o,h,w] = mean_c x1[b,c,h,w] * x2[b,c,h+dh,w+dw]
// B=8 C=128 H=W=128, d=4 -> 81 offsets (o = (dh+4)*9 + (dw+4)).
//
// R4: decomposition change. R2/R3 (88.6 us): NDH=3 dh per 256-thr WG,
// 4px/thread -> acc[3][9] f4 = 108 regs forced into AGPRs (~188 total/wave)
// -> only 2 WGs/CU resident (measured Occupancy 28%), both pipes <50% busy.
// R4: one dh per WG (9x WGs, grid 2304), 8px/thread:
//  - acc = 9dw x 2 f4 = 72 regs -> ~120 total -> 4 waves/SIMD (bounds 128,4)
//  - WG = 128 thr = 2 waves -> ~8 independent WGs/CU; barrier/latency phases
//    of different WGs overlap on the CU
//  - 4 ds_read_b128 feed 72 FMA (18 FMA/read) -> DS-pipe floor ~36 us
//  - LDS 9.2 KB; epilogue sred aliases the idle staging buffer
//  - 8-float lane stride would use only half the LDS bank groups -> XOR
//    swizzle f4 slots by (row&1) on both write and read; epilogue slots
//    swizzled s ^ ((s>>3)&7)
//  - x1 loaded in-iteration (issued before x2 prefetch so vmcnt(3) releases
//    FMAs); x2 double-buffer prefetch issued AFTER the barrier (hipcc drains
//    vmcnt(0) before s_barrier)

constexpr int Cn = 128, Hn = 128, Wn = 128;
constexpr int HWn = Hn * Wn;
constexpr int TH = 4;              // output rows per WG
constexpr int WP = 144;            // floats per LDS row = 36 f4 slots (cols -4..139)
constexpr int HALF_F = TH * WP;    // 576 floats per channel-half
constexpr int BUF_F  = 2 * HALF_F; // 1152 floats per buffer
constexpr int NSLOT  = 280;        // f4 staging slots/channel: 2 halves * 4 rows * 35

__global__ __launch_bounds__(128, 4)
void corr_kernel(const float* __restrict__ x1, const float* __restrict__ x2,
                 float* __restrict__ out) {
  __shared__ float s2[2][2][TH][WP];  // [buf][half][row][colidx] ; 9216 B

  const int t    = threadIdx.x;   // 0..127
  const int half = t >> 6;        // wave index == channel half
  const int q    = t & 63;
  const int row  = q >> 4;        // 0..3
  const int w0   = (q & 15) << 3; // 0,8,...,120

  // XCD swizzle: batch == XCD id (round-robin dispatch assumption); the 9 dh
  // WGs of a tile + 32 tiles of one batch share that XCD's L2 (x1 re-read 9x
  // from L2, not HBM).
  const int phys = blockIdx.x;    // 0..2303
  const int b    = phys & 7;
  const int slot = phys >> 3;     // 0..287
  const int tile = slot / 9;      // 0..31
  const int dhi  = slot - tile * 9;
  const int h0   = tile * TH;
  const int dh   = dhi - 4;

  // ---- staging slots: i = t, t+128, t+256 (third active iff t < 24) ----
  const bool act2 = (t < NSLOT - 256);
  const float* p2k[3];
  float* lwk[3];
  bool okk[3];
#pragma unroll
  for (int k = 0; k < 3; ++k) {
    int i = t + (k << 7);
    if (k == 2 && !act2) i = 0;          // keep derived values in range
    const int hk  = i / 140;             // which channel-half this slot feeds
    const int rem = i - 140 * hk;
    const int sr  = rem / 35;            // staged row 0..3
    const int fc  = rem - 35 * sr;       // f4 col slot 0..34 (cols fc*4-4..fc*4-1)
    const int gr  = h0 + dh + sr;        // global x2 row
    const bool ok = ((unsigned)gr < (unsigned)Hn) && (fc >= 1) && (fc <= 32);
    okk[k] = ok && (k < 2 || act2);
    const int grc = ok ? gr : 0;         // keep formed pointers in-bounds
    const int fcc = ok ? fc : 1;
    p2k[k] = x2 + ((size_t)(b * Cn + hk * 64)) * HWn + grc * Wn + (fcc * 4 - 4);
    lwk[k] = &s2[0][0][0][0] + hk * HALF_F + sr * WP + ((fc ^ (sr & 1)) << 2);
  }

  // x1: loaded per-iteration (8 px = 2 f4)
  const float* p1 = x1 + ((size_t)(b * Cn + half * 64)) * HWn
                       + (size_t)(h0 + row) * Wn + w0;

  // LDS read addrs (swizzled), buffer 0; add bo per iter
  const int rx = row & 1;
  const float* lr[4];
#pragma unroll
  for (int j = 0; j < 4; ++j) {
    const int sl = (w0 >> 2) + j;
    lr[j] = &s2[0][0][0][0] + half * HALF_F + row * WP + ((sl ^ rx) << 2);
  }

  float4 acc[9][2];
#pragma unroll
  for (int dw = 0; dw < 9; ++dw) {
    acc[dw][0] = make_float4(0.f, 0.f, 0.f, 0.f);
    acc[dw][1] = make_float4(0.f, 0.f, 0.f, 0.f);
  }

  // prologue: channel 0 staging prefetch
  float4 pv0 = make_float4(0.f, 0.f, 0.f, 0.f), pv1 = pv0, pv2 = pv0;
  if (okk[0]) pv0 = *(const float4*)p2k[0];
  if (okk[1]) pv1 = *(const float4*)p2k[1];
  if (okk[2]) pv2 = *(const float4*)p2k[2];

#pragma unroll 1
  for (int cc = 0; cc < 64; ++cc) {
    const int bo = (cc & 1) * BUF_F;
    *(float4*)(lwk[0] + bo) = pv0;
    *(float4*)(lwk[1] + bo) = pv1;
    if (act2) *(float4*)(lwk[2] + bo) = pv2;
    __syncthreads();
    // x1 for THIS channel, issued first -> oldest in vmcnt queue; FMAs can
    // start at vmcnt(3) with the x2 prefetch still in flight
    const float4 a0 = *(const float4*)(p1);
    const float4 a1 = *(const float4*)(p1 + 4);
    p1 += HWn;
    // x2 prefetch for next channel (consumed at next iter's ds_write)
    if (cc < 63) {
      p2k[0] += HWn; p2k[1] += HWn; p2k[2] += HWn;
      if (okk[0]) pv0 = *(const float4*)p2k[0];
      if (okk[1]) pv1 = *(const float4*)p2k[1];
      if (okk[2]) pv2 = *(const float4*)p2k[2];
    }
    const float4 wv0 = *(const float4*)(lr[0] + bo);
    const float4 wv1 = *(const float4*)(lr[1] + bo);
    const float4 wv2 = *(const float4*)(lr[2] + bo);
    const float4 wv3 = *(const float4*)(lr[3] + bo);
    const float win[16] = {wv0.x, wv0.y, wv0.z, wv0.w, wv1.x, wv1.y, wv1.z, wv1.w,
                           wv2.x, wv2.y, wv2.z, wv2.w, wv3.x, wv3.y, wv3.z, wv3.w};
    const float av[8] = {a0.x, a0.y, a0.z, a0.w, a1.x, a1.y, a1.z, a1.w};
#pragma unroll
    for (int dw = 0; dw < 9; ++dw) {
      acc[dw][0].x += av[0] * win[dw + 0];
      acc[dw][0].y += av[1] * win[dw + 1];
      acc[dw][0].z += av[2] * win[dw + 2];
      acc[dw][0].w += av[3] * win[dw + 3];
      acc[dw][1].x += av[4] * win[dw + 4];
      acc[dw][1].y += av[5] * win[dw + 5];
      acc[dw][1].z += av[6] * win[dw + 6];
      acc[dw][1].w += av[7] * win[dw + 7];
    }
  }

  // ---- cross-half reduction: wave1 -> LDS (aliases buf0 region, disjoint
  // from buf1 which wave0 last read; separated by iter-63's barrier), wave0
  // adds + scales + stores. f4 slots XOR-swizzled to spread 8 bank groups.
  float* sb = &s2[0][0][0][0];
  const int s0i = (2 * q);
  const int s1i = (2 * q + 1);
  const int us0 = s0i ^ ((s0i >> 3) & 7);
  const int us1 = s1i ^ ((s1i >> 3) & 7);
  const float scale = 1.0f / 128.0f;
  float* ob = out + ((size_t)b * 81 + (size_t)dhi * 9) * HWn
                  + (size_t)(h0 + row) * Wn + w0;
#pragma unroll 1
  for (int dw = 0; dw < 9; ++dw) {
    if (half) {
      *(float4*)(sb + (us0 << 2)) = acc[dw][0];
      *(float4*)(sb + (us1 << 2)) = acc[dw][1];
    }
    __syncthreads();
    if (!half) {
      const float4 s0 = *(const float4*)(sb + (us0 << 2));
      const float4 s1 = *(const float4*)(sb + (us1 << 2));
      float4 r0, r1;
      r0.x = (acc[dw][0].x + s0.x) * scale;
      r0.y = (acc[dw][0].y + s0.y) * scale;
      r0.z = (acc[dw][0].z + s0.z) * scale;
      r0.w = (acc[dw][0].w + s0.w) * scale;
      r1.x = (acc[dw][1].x + s1.x) * scale;
      r1.y = (acc[dw][1].y + s1.y) * scale;
      r1.z = (acc[dw][1].z + s1.z) * scale;
      r1.w = (acc[dw][1].w + s1.w) * scale;
      *(float4*)(ob + (size_t)dw * HWn) = r0;
      *(float4*)(ob + (size_t)dw * HWn + 4) = r1;
    }
    __syncthreads();
  }
}

extern "C" void kernel_launch(void* const* d_in, const int* in_sizes, int n_in,
                              void* d_out, int out_size, void* d_ws, size_t ws_size,
                              hipStream_t stream) {
  const float* x1 = (const float*)d_in[0];
  const float* x2 = (const float*)d_in[1];
  float* out = (float*)d_out;
  const int n_wgs = 8 * (Hn / TH) * 9;  // 2304 = 9 per CU
  corr_kernel<<<dim3(n_wgs), dim3(128), 0, stream>>>(x1, x2, out);
}

// Round 3
// 254.223 us; speedup vs baseline: 7.2172x; 7.2172x over previous
//
#include <hip/hip_runtime.h>

// Correlation layer: out[b,o,h,w] = mean_c x1[b,c,h,w] * x2[b,c,h+dh,w+dw]
// B=8 C=128 H=W=128, d=4 -> 81 offsets (o = (dh+4)*9 + (dw+4)).
//
// R5 = R4 with the scratch-spill bug fixed.
// R4 (1754 us!): epilogue reduction loop was `#pragma unroll 1` and indexed
// acc[dw] with RUNTIME dw -> rule #20: the whole acc[9][2] array was demoted
// to scratch for the WHOLE kernel (VGPR_Count=32, WRITE_SIZE 5.3 GB of spill
// traffic, VALUBusy 1.6%). Fix: fully unroll the epilogue dw loop so every
// acc access is compile-time indexed.
//
// R4 design (unchanged): one dh per WG (grid 2304), 8px/thread:
//  - acc = 9dw x 2 f4 = 72 regs -> ~120 total -> 4 waves/SIMD (bounds 128,4)
//  - WG = 128 thr = 2 waves -> ~8 independent WGs/CU; barrier/latency phases
//    of different WGs overlap on the CU
//  - 4 ds_read_b128 feed 72 FMA (18 FMA/read) -> DS-pipe floor ~36 us
//  - LDS 9.2 KB; epilogue sred aliases the idle staging buffer
//  - XOR swizzle f4 slots by (row&1) on write+read; epilogue s ^ ((s>>3)&7)
//  - x1 loaded in-iteration (issued before x2 prefetch); x2 double-buffer
//    prefetch issued AFTER the barrier (hipcc drains vmcnt(0) before
//    s_barrier)

constexpr int Cn = 128, Hn = 128, Wn = 128;
constexpr int HWn = Hn * Wn;
constexpr int TH = 4;              // output rows per WG
constexpr int WP = 144;            // floats per LDS row = 36 f4 slots (cols -4..139)
constexpr int HALF_F = TH * WP;    // 576 floats per channel-half
constexpr int BUF_F  = 2 * HALF_F; // 1152 floats per buffer
constexpr int NSLOT  = 280;        // f4 staging slots/channel: 2 halves * 4 rows * 35

__global__ __launch_bounds__(128, 4)
void corr_kernel(const float* __restrict__ x1, const float* __restrict__ x2,
                 float* __restrict__ out) {
  __shared__ float s2[2][2][TH][WP];  // [buf][half][row][colidx] ; 9216 B

  const int t    = threadIdx.x;   // 0..127
  const int half = t >> 6;        // wave index == channel half
  const int q    = t & 63;
  const int row  = q >> 4;        // 0..3
  const int w0   = (q & 15) << 3; // 0,8,...,120

  // XCD swizzle: batch == XCD id (round-robin dispatch assumption); the 9 dh
  // WGs of a tile + 32 tiles of one batch share that XCD's L2 (x1 re-read 9x
  // from L2, not HBM).
  const int phys = blockIdx.x;    // 0..2303
  const int b    = phys & 7;
  const int slot = phys >> 3;     // 0..287
  const int tile = slot / 9;      // 0..31
  const int dhi  = slot - tile * 9;
  const int h0   = tile * TH;
  const int dh   = dhi - 4;

  // ---- staging slots: i = t, t+128, t+256 (third active iff t < 24) ----
  const bool act2 = (t < NSLOT - 256);
  const float* p2k[3];
  float* lwk[3];
  bool okk[3];
#pragma unroll
  for (int k = 0; k < 3; ++k) {
    int i = t + (k << 7);
    if (k == 2 && !act2) i = 0;          // keep derived values in range
    const int hk  = i / 140;             // which channel-half this slot feeds
    const int rem = i - 140 * hk;
    const int sr  = rem / 35;            // staged row 0..3
    const int fc  = rem - 35 * sr;       // f4 col slot 0..34 (cols fc*4-4..fc*4-1)
    const int gr  = h0 + dh + sr;        // global x2 row
    const bool ok = ((unsigned)gr < (unsigned)Hn) && (fc >= 1) && (fc <= 32);
    okk[k] = ok && (k < 2 || act2);
    const int grc = ok ? gr : 0;         // keep formed pointers in-bounds
    const int fcc = ok ? fc : 1;
    p2k[k] = x2 + ((size_t)(b * Cn + hk * 64)) * HWn + grc * Wn + (fcc * 4 - 4);
    lwk[k] = &s2[0][0][0][0] + hk * HALF_F + sr * WP + ((fc ^ (sr & 1)) << 2);
  }

  // x1: loaded per-iteration (8 px = 2 f4)
  const float* p1 = x1 + ((size_t)(b * Cn + half * 64)) * HWn
                       + (size_t)(h0 + row) * Wn + w0;

  // LDS read addrs (swizzled), buffer 0; add bo per iter
  const int rx = row & 1;
  const float* lr[4];
#pragma unroll
  for (int j = 0; j < 4; ++j) {
    const int sl = (w0 >> 2) + j;
    lr[j] = &s2[0][0][0][0] + half * HALF_F + row * WP + ((sl ^ rx) << 2);
  }

  float4 acc[9][2];
#pragma unroll
  for (int dw = 0; dw < 9; ++dw) {
    acc[dw][0] = make_float4(0.f, 0.f, 0.f, 0.f);
    acc[dw][1] = make_float4(0.f, 0.f, 0.f, 0.f);
  }

  // prologue: channel 0 staging prefetch
  float4 pv0 = make_float4(0.f, 0.f, 0.f, 0.f), pv1 = pv0, pv2 = pv0;
  if (okk[0]) pv0 = *(const float4*)p2k[0];
  if (okk[1]) pv1 = *(const float4*)p2k[1];
  if (okk[2]) pv2 = *(const float4*)p2k[2];

#pragma unroll 1
  for (int cc = 0; cc < 64; ++cc) {
    const int bo = (cc & 1) * BUF_F;
    *(float4*)(lwk[0] + bo) = pv0;
    *(float4*)(lwk[1] + bo) = pv1;
    if (act2) *(float4*)(lwk[2] + bo) = pv2;
    __syncthreads();
    // x1 for THIS channel, issued first -> oldest in vmcnt queue; FMAs can
    // start at vmcnt(3) with the x2 prefetch still in flight
    const float4 a0 = *(const float4*)(p1);
    const float4 a1 = *(const float4*)(p1 + 4);
    p1 += HWn;
    // x2 prefetch for next channel (consumed at next iter's ds_write)
    if (cc < 63) {
      p2k[0] += HWn; p2k[1] += HWn; p2k[2] += HWn;
      if (okk[0]) pv0 = *(const float4*)p2k[0];
      if (okk[1]) pv1 = *(const float4*)p2k[1];
      if (okk[2]) pv2 = *(const float4*)p2k[2];
    }
    const float4 wv0 = *(const float4*)(lr[0] + bo);
    const float4 wv1 = *(const float4*)(lr[1] + bo);
    const float4 wv2 = *(const float4*)(lr[2] + bo);
    const float4 wv3 = *(const float4*)(lr[3] + bo);
    const float win[16] = {wv0.x, wv0.y, wv0.z, wv0.w, wv1.x, wv1.y, wv1.z, wv1.w,
                           wv2.x, wv2.y, wv2.z, wv2.w, wv3.x, wv3.y, wv3.z, wv3.w};
    const float av[8] = {a0.x, a0.y, a0.z, a0.w, a1.x, a1.y, a1.z, a1.w};
#pragma unroll
    for (int dw = 0; dw < 9; ++dw) {
      acc[dw][0].x += av[0] * win[dw + 0];
      acc[dw][0].y += av[1] * win[dw + 1];
      acc[dw][0].z += av[2] * win[dw + 2];
      acc[dw][0].w += av[3] * win[dw + 3];
      acc[dw][1].x += av[4] * win[dw + 4];
      acc[dw][1].y += av[5] * win[dw + 5];
      acc[dw][1].z += av[6] * win[dw + 6];
      acc[dw][1].w += av[7] * win[dw + 7];
    }
  }

  // ---- cross-half reduction: wave1 -> LDS (aliases buf0 region, disjoint
  // from buf1 which wave0 last read; separated by iter-63's barrier), wave0
  // adds + scales + stores. FULLY UNROLLED so acc indexing stays static
  // (rule #20: a single runtime index demotes the whole array to scratch).
  float* sb = &s2[0][0][0][0];
  const int s0i = (2 * q);
  const int s1i = (2 * q + 1);
  const int us0 = s0i ^ ((s0i >> 3) & 7);
  const int us1 = s1i ^ ((s1i >> 3) & 7);
  const float scale = 1.0f / 128.0f;
  float* ob = out + ((size_t)b * 81 + (size_t)dhi * 9) * HWn
                  + (size_t)(h0 + row) * Wn + w0;
#pragma unroll
  for (int dw = 0; dw < 9; ++dw) {
    if (half) {
      *(float4*)(sb + (us0 << 2)) = acc[dw][0];
      *(float4*)(sb + (us1 << 2)) = acc[dw][1];
    }
    __syncthreads();
    if (!half) {
      const float4 s0 = *(const float4*)(sb + (us0 << 2));
      const float4 s1 = *(const float4*)(sb + (us1 << 2));
      float4 r0, r1;
      r0.x = (acc[dw][0].x + s0.x) * scale;
      r0.y = (acc[dw][0].y + s0.y) * scale;
      r0.z = (acc[dw][0].z + s0.z) * scale;
      r0.w = (acc[dw][0].w + s0.w) * scale;
      r1.x = (acc[dw][1].x + s1.x) * scale;
      r1.y = (acc[dw][1].y + s1.y) * scale;
      r1.z = (acc[dw][1].z + s1.z) * scale;
      r1.w = (acc[dw][1].w + s1.w) * scale;
      *(float4*)(ob + (size_t)dw * HWn) = r0;
      *(float4*)(ob + (size_t)dw * HWn + 4) = r1;
    }
    __syncthreads();
  }
}

extern "C" void kernel_launch(void* const* d_in, const int* in_sizes, int n_in,
                              void* d_out, int out_size, void* d_ws, size_t ws_size,
                              hipStream_t stream) {
  const float* x1 = (const float*)d_in[0];
  const float* x2 = (const float*)d_in[1];
  float* out = (float*)d_out;
  const int n_wgs = 8 * (Hn / TH) * 9;  // 2304 = 9 per CU
  corr_kernel<<<dim3(n_wgs), dim3(128), 0, stream>>>(x1, x2, out);
}

// Round 4
// 224.521 us; speedup vs baseline: 8.1719x; 1.1323x over previous
//
#include <hip/hip_runtime.h>

// Correlation layer: out[b,o,h,w] = mean_c x1[b,c,h,w] * x2[b,c,h+dh,w+dw]
// B=8 C=128 H=W=128, d=4 -> 81 offsets (o = (dh+4)*9 + (dw+4)).
//
// R6: LDS-free rewrite. R3 (88us) was LDS-pipe+barrier bound (DS floor
// ~42us); R5 (148us) added in-loop x1 latency + reg-capped occupancy.
// Key insight: the LDS staging only provides +-4-shifted windows; a
// 16-lane DPP row holds the full 128-px image row in registers (8px/lane),
// so row_shr:1 / row_shl:1 (bound_ctrl=1 zero-fill == zero-pad at w edges)
// deliver the halo for free on the VALU pipe:
//   win[0..3]  = left lane's hi f4 = dpp_shr1(b1)
//   win[4..11] = own b0,b1
//   win[12..15]= right lane's lo f4 = dpp_shl1(b0)
// okr (h-edge zero rows) is uniform across each 16-lane DPP row.
//
// Structure: 64-thr (1-wave) WGs, 4 rows x 16 lanes x 8 px, each wave runs
// ALL 128 channels -> no reduction, no LDS, no barriers. 2-deep register
// prefetch of x1/x2 (4 f4/channel) hides L2/L3 latency. Grid 2304 = exactly
// 9 waves/CU; XCD swizzle (b = phys&7) keeps one batch per XCD L2.
// VALU floor ~21us (72 FMA + 8 DPP + ~4 addr per ch), HBM floor ~17-26us.

constexpr int Cn = 128, Hn = 128, Wn = 128;
constexpr int HWn = Hn * Wn;
constexpr int TH = 4;

__device__ __forceinline__ float dpp_shr1(float x) {  // lane l <- lane l-1 (0-fill)
  return __int_as_float(__builtin_amdgcn_update_dpp(
      0, __float_as_int(x), 0x111, 0xF, 0xF, true));
}
__device__ __forceinline__ float dpp_shl1(float x) {  // lane l <- lane l+1 (0-fill)
  return __int_as_float(__builtin_amdgcn_update_dpp(
      0, __float_as_int(x), 0x101, 0xF, 0xF, true));
}

__global__ __launch_bounds__(64, 3)
void corr_kernel(const float* __restrict__ x1, const float* __restrict__ x2,
                 float* __restrict__ out) {
  const int t   = threadIdx.x;     // 0..63
  const int row = t >> 4;          // 0..3  (== DPP row group)
  const int w0  = (t & 15) << 3;   // 0,8,...,120

  const int phys = blockIdx.x;     // 0..2303
  const int b    = phys & 7;       // batch == XCD (round-robin assumption)
  const int slot = phys >> 3;      // 0..287
  const int tile = slot / 9;       // 0..31
  const int dhi  = slot - tile * 9;
  const int h0   = tile * TH;
  const int dh   = dhi - 4;

  const int grow  = h0 + row + dh;                 // x2 source row
  const bool okr  = (unsigned)grow < (unsigned)Hn; // uniform per 16-lane row
  const int growc = okr ? grow : 0;

  const float* p1 = x1 + (size_t)b * Cn * HWn + (size_t)(h0 + row) * Wn + w0;
  const float* p2 = x2 + (size_t)b * Cn * HWn + (size_t)growc * Wn + w0;

  float4 acc0[9], acc1[9];
#pragma unroll
  for (int dw = 0; dw < 9; ++dw) {
    acc0[dw] = make_float4(0.f, 0.f, 0.f, 0.f);
    acc1[dw] = make_float4(0.f, 0.f, 0.f, 0.f);
  }

  // 2-deep prefetch buffers (static [s] indexing via unroll-2)
  float4 A[2], B[2], C[2], D[2];
  const float4 z4 = make_float4(0.f, 0.f, 0.f, 0.f);
  A[0] = *(const float4*)p1;
  B[0] = *(const float4*)(p1 + 4);
  C[0] = z4; D[0] = z4;
  if (okr) { C[0] = *(const float4*)p2; D[0] = *(const float4*)(p2 + 4); }
  A[1] = *(const float4*)(p1 + HWn);
  B[1] = *(const float4*)(p1 + HWn + 4);
  C[1] = z4; D[1] = z4;
  if (okr) { C[1] = *(const float4*)(p2 + HWn); D[1] = *(const float4*)(p2 + HWn + 4); }
  p1 += 2 * HWn;
  p2 += 2 * HWn;

#pragma unroll 2
  for (int cc = 0; cc < Cn; ++cc) {
    const int s = cc & 1;          // static after unroll-2
    const float4 a0 = A[s], a1 = B[s];
    const float4 b0 = C[s], b1 = D[s];
    if (cc < Cn - 2) {             // prefetch channel cc+2 into slot s
      A[s] = *(const float4*)p1;
      B[s] = *(const float4*)(p1 + 4);
      if (okr) { C[s] = *(const float4*)p2; D[s] = *(const float4*)(p2 + 4); }
      p1 += HWn;
      p2 += HWn;
    }
    // window win[k] = x2[w0 + k - 4], k = 0..15
    const float win[16] = {
        dpp_shr1(b1.x), dpp_shr1(b1.y), dpp_shr1(b1.z), dpp_shr1(b1.w),
        b0.x, b0.y, b0.z, b0.w,
        b1.x, b1.y, b1.z, b1.w,
        dpp_shl1(b0.x), dpp_shl1(b0.y), dpp_shl1(b0.z), dpp_shl1(b0.w)};
    const float av[8] = {a0.x, a0.y, a0.z, a0.w, a1.x, a1.y, a1.z, a1.w};
#pragma unroll
    for (int dw = 0; dw < 9; ++dw) {
      acc0[dw].x += av[0] * win[dw + 0];
      acc0[dw].y += av[1] * win[dw + 1];
      acc0[dw].z += av[2] * win[dw + 2];
      acc0[dw].w += av[3] * win[dw + 3];
      acc1[dw].x += av[4] * win[dw + 4];
      acc1[dw].y += av[5] * win[dw + 5];
      acc1[dw].z += av[6] * win[dw + 6];
      acc1[dw].w += av[7] * win[dw + 7];
    }
  }

  // epilogue: scale + store (no reduction needed; this wave owns 128 ch)
  const float scale = 1.0f / 128.0f;
  float* ob = out + ((size_t)b * 81 + (size_t)dhi * 9) * HWn
                  + (size_t)(h0 + row) * Wn + w0;
#pragma unroll
  for (int dw = 0; dw < 9; ++dw) {
    float4 r0, r1;
    r0.x = acc0[dw].x * scale; r0.y = acc0[dw].y * scale;
    r0.z = acc0[dw].z * scale; r0.w = acc0[dw].w * scale;
    r1.x = acc1[dw].x * scale; r1.y = acc1[dw].y * scale;
    r1.z = acc1[dw].z * scale; r1.w = acc1[dw].w * scale;
    *(float4*)(ob + (size_t)dw * HWn) = r0;
    *(float4*)(ob + (size_t)dw * HWn + 4) = r1;
  }
}

extern "C" void kernel_launch(void* const* d_in, const int* in_sizes, int n_in,
                              void* d_out, int out_size, void* d_ws, size_t ws_size,
                              hipStream_t stream) {
  const float* x1 = (const float*)d_in[0];
  const float* x2 = (const float*)d_in[1];
  float* out = (float*)d_out;
  const int n_wgs = 8 * (Hn / TH) * 9;  // 2304 single-wave WGs = 9 waves/CU
  corr_kernel<<<dim3(n_wgs), dim3(64), 0, stream>>>(x1, x2, out);
}

// Round 5
// 177.714 us; speedup vs baseline: 10.3243x; 1.2634x over previous
//
#include <hip/hip_runtime.h>

// Correlation layer: out[b,o,h,w] = mean_c x1[b,c,h,w] * x2[b,c,h+dh,w+dw]
// B=8 C=128 H=W=128, d=4 -> 81 offsets (o = (dh+4)*9 + (dw+4)).
//
// R7: 9-dh workgroup. R6 (120us) was L3-BW-bound: 1 dh per wave meant x1
// AND x2 each read 9x (1.18 GB logical @ ~9.8 TB/s == L3 service ceiling).
// R7 stages the 16 rows a 4-row tile needs (4 x1 + 12 x2) ONCE in LDS per
// channel; 9 waves (one per dh) consume them -> logical reads 0.26 GB.
// Each wave keeps R6's verified register structure: 8px/lane, DPP
// row_shr1/row_shl1 halo (bound_ctrl=1 zero-fill == zero-pad at w edges),
// acc[9 dw] x 2 f4.
//  - LDS row layout "split-halves": floats [0..63] = low f4 of lane l at
//    4l (px 8l..8l+3), [64..127] = high f4 (px 8l+4..8l+7). All 4
//    ds_read_b128/lane are 16B-lane-stride -> conflict-free. Staging
//    thread slot s writes float offset 4s (sequential -> conflict-free)
//    and loads the matching global f4 j = (s<16) ? 2s : 2(s-16)+1.
//  - 2 channels per barrier (double-buffered 2-ch slabs, 32 KB LDS):
//    64 barriers total, ~700cyc compute/barrier hides the after-barrier
//    global prefetch (1 f4/thread/channel). Grid 256 = 1 WG/CU.
//  - OOB x2 rows (h edge) stage ZEROS (pv stays 0, write unconditional).

constexpr int Cn = 128, Hn = 128, Wn = 128;
constexpr int HWn = Hn * Wn;
constexpr int TH = 4;
constexpr int NROWS = 16;           // 4 x1 rows + 12 x2 rows
constexpr int ROWF  = 128;          // floats per LDS row
constexpr int CHF   = NROWS * ROWF; // 2048 floats per channel slab
constexpr int BUFF  = 2 * CHF;      // buffer = 2 channel slabs

__device__ __forceinline__ float dpp_shr1(float x) {  // lane l <- lane l-1 (0-fill)
  return __int_as_float(__builtin_amdgcn_update_dpp(
      0, __float_as_int(x), 0x111, 0xF, 0xF, true));
}
__device__ __forceinline__ float dpp_shl1(float x) {  // lane l <- lane l+1 (0-fill)
  return __int_as_float(__builtin_amdgcn_update_dpp(
      0, __float_as_int(x), 0x101, 0xF, 0xF, true));
}

__global__ __launch_bounds__(576, 3)
void corr_kernel(const float* __restrict__ x1, const float* __restrict__ x2,
                 float* __restrict__ out) {
  __shared__ float lds[2][2][NROWS][ROWF];  // [buf][ch][row][float] ; 32 KB

  const int t    = threadIdx.x;  // 0..575
  const int w    = t >> 6;       // wave 0..8 -> dh = w-4
  const int lane = t & 63;
  const int r    = lane >> 4;    // output row 0..3
  const int l    = lane & 15;    // px group: px 8l..8l+7

  const int phys = blockIdx.x;   // 0..255 (1 per CU)
  const int b    = phys & 7;     // batch == XCD (round-robin assumption)
  const int tile = phys >> 3;    // 0..31
  const int h0   = tile * TH;
  const int dh   = w - 4;

  // ---- staging assignment (threads 0..511: one f4 per channel) ----
  const bool stg  = t < 512;
  const int ridx  = t >> 5;      // LDS row 0..15 (valid for t<512)
  const int s     = t & 31;      // f4 slot within row
  const int j     = (s < 16) ? (s << 1) : (((s - 16) << 1) | 1); // global f4
  int gr;
  bool okg;
  if (ridx < 4) { gr = h0 + ridx; okg = true; }            // x1 rows 0..3
  else { gr = h0 + ridx - 8; okg = (unsigned)gr < (unsigned)Hn; } // x2 -4..+7
  const float* src = (ridx < 4 ? x1 : x2) + (size_t)b * Cn * HWn
                   + (size_t)(okg ? gr : 0) * Wn + (j << 2);
  okg = okg && stg;
  float* const L = &lds[0][0][0][0];
  const int woff = ridx * ROWF + (s << 2);  // write float offset within slab

  // ---- per-wave read offsets (within slab) ----
  const int rx  = r + dh + 8;               // staged x2 row index 4..15
  const int o1l = r * ROWF + (l << 2);      // x1 low f4
  const int o1h = o1l + 64;                 // x1 high f4
  const int o2l = rx * ROWF + (l << 2);     // x2 low f4
  const int o2h = o2l + 64;                 // x2 high f4

  float4 acc0[9], acc1[9];
#pragma unroll
  for (int dw = 0; dw < 9; ++dw) {
    acc0[dw] = make_float4(0.f, 0.f, 0.f, 0.f);
    acc1[dw] = make_float4(0.f, 0.f, 0.f, 0.f);
  }

  // prologue: prefetch channels 0,1
  const float4 z4 = make_float4(0.f, 0.f, 0.f, 0.f);
  float4 pv0 = z4, pv1 = z4;
  if (okg) { pv0 = *(const float4*)src; pv1 = *(const float4*)(src + HWn); }
  src += 2 * HWn;

#pragma unroll 1
  for (int step = 0; step < 64; ++step) {
    const int bo = (step & 1) * BUFF;
    if (stg) {
      *(float4*)(L + bo + woff)       = pv0;   // channel 2*step
      *(float4*)(L + bo + CHF + woff) = pv1;   // channel 2*step+1
    }
    __syncthreads();
    // prefetch next 2 channels AFTER the barrier (hipcc drains vmcnt(0)
    // before s_barrier); consumed at next iter's ds_write
    if (okg && step < 63) {
      pv0 = *(const float4*)src;
      pv1 = *(const float4*)(src + HWn);
    }
    src += 2 * HWn;

#pragma unroll
    for (int ch = 0; ch < 2; ++ch) {
      const float* p = L + bo + ch * CHF;
      const float4 a0 = *(const float4*)(p + o1l);
      const float4 a1 = *(const float4*)(p + o1h);
      const float4 b0 = *(const float4*)(p + o2l);
      const float4 b1 = *(const float4*)(p + o2h);
      // win[k] = x2[px 8l + k - 4], k = 0..15
      const float win[16] = {
          dpp_shr1(b1.x), dpp_shr1(b1.y), dpp_shr1(b1.z), dpp_shr1(b1.w),
          b0.x, b0.y, b0.z, b0.w,
          b1.x, b1.y, b1.z, b1.w,
          dpp_shl1(b0.x), dpp_shl1(b0.y), dpp_shl1(b0.z), dpp_shl1(b0.w)};
      const float av[8] = {a0.x, a0.y, a0.z, a0.w, a1.x, a1.y, a1.z, a1.w};
#pragma unroll
      for (int dw = 0; dw < 9; ++dw) {
        acc0[dw].x += av[0] * win[dw + 0];
        acc0[dw].y += av[1] * win[dw + 1];
        acc0[dw].z += av[2] * win[dw + 2];
        acc0[dw].w += av[3] * win[dw + 3];
        acc1[dw].x += av[4] * win[dw + 4];
        acc1[dw].y += av[5] * win[dw + 5];
        acc1[dw].z += av[6] * win[dw + 6];
        acc1[dw].w += av[7] * win[dw + 7];
      }
    }
  }

  // ---- epilogue: scale + store (each wave owns its dh entirely) ----
  const float scale = 1.0f / 128.0f;
  float* ob = out + ((size_t)b * 81 + (size_t)w * 9) * HWn
                  + (size_t)(h0 + r) * Wn + (l << 3);
#pragma unroll
  for (int dw = 0; dw < 9; ++dw) {
    float4 r0, r1;
    r0.x = acc0[dw].x * scale; r0.y = acc0[dw].y * scale;
    r0.z = acc0[dw].z * scale; r0.w = acc0[dw].w * scale;
    r1.x = acc1[dw].x * scale; r1.y = acc1[dw].y * scale;
    r1.z = acc1[dw].z * scale; r1.w = acc1[dw].w * scale;
    *(float4*)(ob + (size_t)dw * HWn)     = r0;
    *(float4*)(ob + (size_t)dw * HWn + 4) = r1;
  }
}

extern "C" void kernel_launch(void* const* d_in, const int* in_sizes, int n_in,
                              void* d_out, int out_size, void* d_ws, size_t ws_size,
                              hipStream_t stream) {
  const float* x1 = (const float*)d_in[0];
  const float* x2 = (const float*)d_in[1];
  float* out = (float*)d_out;
  const int n_wgs = 8 * (Hn / TH);  // 256 WGs = 1 per CU
  corr_kernel<<<dim3(n_wgs), dim3(576), 0, stream>>>(x1, x2, out);
}